// Round 1
// baseline (197.908 us; speedup 1.0000x reference)
//
#include <hip/hip_runtime.h>
#include <stdint.h>

// Dyna_Dec: out[b,d,l] = sum_c x[b,c,l] * w[l,c,d] + bias[l,d]
// B=128, C=32, L=4096. fp32 in/out.
//
// R6 counters (88us/dispatch): VALUBusy 12.6%, hbm 16%, Occ 25%, traffic
// compulsory (FETCH 44MB, WRITE 64MB) -> latency/issue bound. Culprit: W
// loads are lane-scattered (4KB stride across 64 lanes) => each wave load
// touches 64 L1 lines; ~27us of serialized tag lookups + unhidden latency.
//
// R7: stage W through LDS. Per c-chunk of 4, the block's W slice
// (64 l x 4 c x 32 d = 32 KB) is loaded with fully-coalesced float4 reads
// (contiguous 512 B per l-row) and written to LDS with a 16B-slot XOR
// swizzle (slot ^ (l&31)) so both ds_write_b128 (staging) and
// ds_read_b128 (compute: same-offset-different-row, naturally 32-way
// conflicted) are evenly bank-distributed. x loads unchanged (coalesced).
// 32 KB LDS -> 4 blocks/CU -> 16 waves/CU. Grid linearization unchanged:
// id%8 == blockIdx.x%8 keeps one l-chunk's W slice on one XCD's L2.

namespace {

constexpr int kC  = 32;
constexpr int kL  = 4096;
constexpr int kNB = 8;   // batches per thread
constexpr int kND = 8;   // d-channels per thread
constexpr int kCC = 4;   // c-chunk staged in LDS per round
constexpr int kLB = 64;  // l-positions per block
constexpr int kRowF = kCC * kC;            // 128 floats per LDS l-row
constexpr int kChunkFloats = kLB * kRowF;  // 8192 floats = 32 KB

__global__ __launch_bounds__(256, 4)
void dyna_dec(const float* __restrict__ x,
              const float* __restrict__ w,
              const float* __restrict__ bias,
              float* __restrict__ out) {
    __shared__ __align__(16) float lds[kChunkFloats];

    const int tid = threadIdx.x;
    const int lt  = tid & 63;          // lane = l within chunk (coalescing dim)
    const int dg  = tid >> 6;          // wave = d-group 0..3
    const int l   = blockIdx.x * kLB + lt;      // gridDim.x = L/64 = 64
    const int b0  = blockIdx.y * kNB;           // gridDim.y = B/8  = 16
    const int d0  = dg * kND;

    const float* xp = x + (size_t)b0 * (kC * kL) + l;           // x[b0, 0, l]
    const float* wb = w + (size_t)blockIdx.x * kLB * (kC * kC); // block's W rows

    float acc[kNB][kND];
#pragma unroll
    for (int i = 0; i < kNB; ++i)
#pragma unroll
        for (int j = 0; j < kND; ++j) acc[i][j] = 0.0f;

    for (int cb = 0; cb < kC; cb += kCC) {
        __syncthreads();  // previous chunk's LDS reads complete

        // Stage W[l0..l0+63, cb..cb+kCC-1, 0..31] -> LDS.
        // 16B slots: s = tid + k*256 in [0,2048); row ls = s>>5, slot cs = s&31.
        // Global: per-row contiguous 512 B (coalesced). LDS: slot XOR (ls&31).
#pragma unroll
        for (int k = 0; k < 8; ++k) {
            const int s  = tid + k * 256;
            const int ls = s >> 5;
            const int cs = s & 31;
            const float4 v = *reinterpret_cast<const float4*>(
                wb + (size_t)ls * (kC * kC) + cb * kC + cs * 4);
            *reinterpret_cast<float4*>(
                &lds[ls * kRowF + ((cs ^ (ls & 31)) << 2)]) = v;
        }
        __syncthreads();  // chunk visible to all waves

#pragma unroll
        for (int c = 0; c < kCC; ++c) {
            // W[l, cb+c, d0..d0+7] = two swizzled 16B slots of row lt
            const int s16 = c * 8 + (d0 >> 2);
            const float4 w0 = *reinterpret_cast<const float4*>(
                &lds[lt * kRowF + (((s16 + 0) ^ (lt & 31)) << 2)]);
            const float4 w1 = *reinterpret_cast<const float4*>(
                &lds[lt * kRowF + (((s16 + 1) ^ (lt & 31)) << 2)]);
            const float ws[kND] = {w0.x, w0.y, w0.z, w0.w,
                                   w1.x, w1.y, w1.z, w1.w};

            // x[b0+i, cb+c, l]: coalesced over lanes, 8 independent loads
            float xr[kNB];
#pragma unroll
            for (int i = 0; i < kNB; ++i)
                xr[i] = xp[(size_t)i * (kC * kL) + (size_t)(cb + c) * kL];

#pragma unroll
            for (int i = 0; i < kNB; ++i)
#pragma unroll
                for (int j = 0; j < kND; ++j)
                    acc[i][j] += xr[i] * ws[j];
        }
    }

    // bias[l, d0..d0+7]
    const float4 b0v = *reinterpret_cast<const float4*>(bias + (size_t)l * kC + d0);
    const float4 b1v = *reinterpret_cast<const float4*>(bias + (size_t)l * kC + d0 + 4);
    const float bv[kND] = {b0v.x, b0v.y, b0v.z, b0v.w, b1v.x, b1v.y, b1v.z, b1v.w};

#pragma unroll
    for (int i = 0; i < kNB; ++i) {
        float* op = out + (size_t)(b0 + i) * (kC * kL) + l;
#pragma unroll
        for (int j = 0; j < kND; ++j)
            op[(size_t)(d0 + j) * kL] = acc[i][j] + bv[j];  // coalesced over l
    }
}

}  // namespace

extern "C" void kernel_launch(void* const* d_in, const int* in_sizes, int n_in,
                              void* d_out, int out_size, void* d_ws, size_t ws_size,
                              hipStream_t stream) {
    // inputs: 0=x (B,C,H,W) fp32, 1=px (unused), 2=weight (L*C, C) fp32,
    //         3=bias (L*C) fp32
    const float* x    = (const float*)d_in[0];
    const float* wgt  = (const float*)d_in[2];
    const float* bias = (const float*)d_in[3];
    float* out = (float*)d_out;

    dim3 grid(kL / 64, 128 / kNB);  // 64 x 16 = 1024 blocks
    dim3 block(256);
    hipLaunchKernelGGL(dyna_dec, grid, block, 0, stream, x, wgt, bias, out);
}